// Round 1
// baseline (190.020 us; speedup 1.0000x reference)
//
#include <hip/hip_runtime.h>
#include <hip/hip_bf16.h>
#include <stdint.h>

#define BB 4
#define NN 2048
#define FF 128

typedef __attribute__((ext_vector_type(8))) short bf16x8;
typedef __attribute__((ext_vector_type(4))) float f32x4;

__device__ inline unsigned pk_bf16(float a, float b) {
    union { float f; unsigned u; } x, y;
    x.f = a; y.f = b;
    unsigned xu = x.u + (0x7fffu + ((x.u >> 16) & 1u));
    unsigned yu = y.u + (0x7fffu + ((y.u >> 16) & 1u));
    return (xu >> 16) | (yu & 0xffff0000u);
}

// ---------------- Kernel 1: h = x@W (fp32), s = h@a_w + a_b, Ht (bf16, transposed) ----
// grid: BB * (NN/16) = 512 blocks, 256 threads
__global__ __launch_bounds__(256) void k1_proj(
    const float* __restrict__ x, const float* __restrict__ W,
    const float* __restrict__ a_w, const float* __restrict__ a_b,
    uint16_t* __restrict__ Ht, float* __restrict__ s_out)
{
    __shared__ float Wl[128 * 128];   // 64 KB
    __shared__ float xl[16 * 128];    // 8 KB
    __shared__ float ht[128 * 17];    // h transposed [g][n], +1 pad
    __shared__ float sred[32];

    const int t = threadIdx.x;
    const int b = blockIdx.x >> 7;
    const int n0 = (blockIdx.x & 127) << 4;

    // stage W coalesced: 16384 floats = 4096 float4
    {
        const float4* Wg = (const float4*)W;
        float4* Wd = (float4*)Wl;
        #pragma unroll
        for (int i = 0; i < 16; ++i) Wd[i * 256 + t] = Wg[i * 256 + t];
    }
    // stage 16 rows of x: 2048 floats = 512 float4
    {
        const float4* xg = (const float4*)(x + ((size_t)(b * NN + n0)) * FF);
        float4* xd = (float4*)xl;
        xd[t] = xg[t];
        xd[256 + t] = xg[256 + t];
    }
    __syncthreads();

    const int c4 = (t & 31) * 4;   // 4 output cols
    const int r0 = t >> 5;         // rows r0 and r0+8
    const int r1 = r0 + 8;
    float acc0[4] = {0.f, 0.f, 0.f, 0.f};
    float acc1[4] = {0.f, 0.f, 0.f, 0.f};

    #pragma unroll 4
    for (int k = 0; k < 128; ++k) {
        float4 wv = *(const float4*)&Wl[k * 128 + c4];
        float x0 = xl[r0 * 128 + k];
        float x1 = xl[r1 * 128 + k];
        acc0[0] += x0 * wv.x; acc0[1] += x0 * wv.y; acc0[2] += x0 * wv.z; acc0[3] += x0 * wv.w;
        acc1[0] += x1 * wv.x; acc1[1] += x1 * wv.y; acc1[2] += x1 * wv.z; acc1[3] += x1 * wv.w;
    }
    #pragma unroll
    for (int i = 0; i < 4; ++i) {
        ht[(c4 + i) * 17 + r0] = acc0[i];
        ht[(c4 + i) * 17 + r1] = acc1[i];
    }
    __syncthreads();

    // s = h @ a_w + a_b  (per row: 32 threads, 2 halves of 64 g each)
    if (t < 32) {
        const int m = t & 15, half = t >> 4;
        float sum = 0.f;
        const int g0 = half * 64;
        for (int g = g0; g < g0 + 64; ++g) sum += ht[g * 17 + m] * a_w[g];
        sred[t] = sum;
    }
    __syncthreads();
    if (t < 16) s_out[b * NN + n0 + t] = sred[t] + sred[16 + t] + a_b[0];

    // write Ht[b][g][n] bf16 (coalesced in n)
    {
        const int nl = t & 15, gb = t >> 4;
        #pragma unroll
        for (int p = 0; p < 8; ++p) {
            const int g = gb + 16 * p;
            float v = ht[g * 17 + nl];
            union { float f; unsigned u; } cv; cv.f = v;
            unsigned uu = cv.u + (0x7fffu + ((cv.u >> 16) & 1u));
            Ht[((size_t)(b * 128 + g)) * NN + n0 + nl] = (uint16_t)(uu >> 16);
        }
    }
}

// ---------------- Kernel 2: fused scores + softmax + P@H ----------------------------
// grid: BB * (NN/32) = 256 blocks, 512 threads (8 waves).
// Wave w handles j-chunks c == w (mod 8), chunk = 32 j's. No max-subtraction
// needed (logits bounded ~11). Each lane computes its own MFMA A-fragment of P.
__global__ __launch_bounds__(512) void k2_attn(
    const float* __restrict__ A, const uint16_t* __restrict__ Ht,
    const float* __restrict__ s, const float* __restrict__ bias,
    float* __restrict__ out)
{
    __shared__ float Op[32 * 132];      // O partial accumulation (padded stride)
    __shared__ float rsums[32];
    __shared__ float rsp[8 * 2 * 64];   // per-(wave,rowtile,lane) row-sum partials

    const int t = threadIdx.x;
    const int w = t >> 6, l = t & 63;
    const int b = blockIdx.x >> 6;
    const int i0 = (blockIdx.x & 63) << 5;
    const int m16 = l & 15, q = l >> 4;

    for (int i = t; i < 32 * 132; i += 512) Op[i] = 0.f;
    __syncthreads();

    const float* sb = s + b * NN;
    const float* A0 = A + ((size_t)b * NN + i0 + m16) * NN;
    const float* A1 = A0 + (size_t)16 * NN;
    const uint16_t* Hb = Ht + (size_t)b * 128 * NN;
    const float si0 = sb[i0 + m16];
    const float si1 = sb[i0 + 16 + m16];

    f32x4 acc0[8] = {};
    f32x4 acc1[8] = {};
    float rs0 = 0.f, rs1 = 0.f;

    for (int c = w; c < 64; c += 8) {
        const int jb = c * 32 + q * 8;   // this lane's 8 j's
        float4 sjA = *(const float4*)(sb + jb);
        float4 sjB = *(const float4*)(sb + jb + 4);
        float4 aA0 = *(const float4*)(A0 + jb);
        float4 aB0 = *(const float4*)(A0 + jb + 4);
        float4 aA1 = *(const float4*)(A1 + jb);
        float4 aB1 = *(const float4*)(A1 + jb + 4);

        float sj[8] = {sjA.x, sjA.y, sjA.z, sjA.w, sjB.x, sjB.y, sjB.z, sjB.w};
        float av0[8] = {aA0.x, aA0.y, aA0.z, aA0.w, aB0.x, aB0.y, aB0.z, aB0.w};
        float av1[8] = {aA1.x, aA1.y, aA1.z, aA1.w, aB1.x, aB1.y, aB1.z, aB1.w};

        float p0[8], p1[8];
        #pragma unroll
        for (int j = 0; j < 8; ++j) {
            float e0 = si0 + sj[j]; e0 = fmaxf(e0, 0.2f * e0);   // LeakyReLU(0.2)
            float e1 = si1 + sj[j]; e1 = fmaxf(e1, 0.2f * e1);
            p0[j] = __expf(e0 + av0[j]);
            p1[j] = __expf(e1 + av1[j]);
            rs0 += p0[j]; rs1 += p1[j];
        }
        union { unsigned u[4]; bf16x8 v; } fa0, fa1;
        #pragma unroll
        for (int j = 0; j < 4; ++j) {
            fa0.u[j] = pk_bf16(p0[2 * j], p0[2 * j + 1]);
            fa1.u[j] = pk_bf16(p1[2 * j], p1[2 * j + 1]);
        }
        #pragma unroll
        for (int t8 = 0; t8 < 8; ++t8) {
            bf16x8 hb = *(const bf16x8*)(Hb + ((size_t)(t8 * 16 + m16)) * NN + jb);
            acc0[t8] = __builtin_amdgcn_mfma_f32_16x16x32_bf16(fa0.v, hb, acc0[t8], 0, 0, 0);
            acc1[t8] = __builtin_amdgcn_mfma_f32_16x16x32_bf16(fa1.v, hb, acc1[t8], 0, 0, 0);
        }
    }

    rsp[(w * 2 + 0) * 64 + l] = rs0;
    rsp[(w * 2 + 1) * 64 + l] = rs1;

    // accumulate O partials across waves (LDS atomics; C-layout: row=q*4+r, col=m16)
    #pragma unroll
    for (int t8 = 0; t8 < 8; ++t8) {
        #pragma unroll
        for (int r = 0; r < 4; ++r) {
            const int row0 = q * 4 + r;
            const int g = t8 * 16 + m16;
            atomicAdd(&Op[row0 * 132 + g], acc0[t8][r]);
            atomicAdd(&Op[(16 + row0) * 132 + g], acc1[t8][r]);
        }
    }
    __syncthreads();

    if (t < 32) {
        const int rt = t >> 4, m = t & 15;
        float sum = 0.f;
        for (int w2 = 0; w2 < 8; ++w2)
            for (int q2 = 0; q2 < 4; ++q2)
                sum += rsp[(w2 * 2 + rt) * 64 + q2 * 16 + m];
        rsums[t] = sum;
    }
    __syncthreads();

    // normalize + bias + write (coalesced in g)
    {
        const int g = t & 127, rb = t >> 7;  // rb 0..3
        #pragma unroll
        for (int p = 0; p < 8; ++p) {
            const int row = rb * 8 + p;
            float v = Op[row * 132 + g] / rsums[row] + bias[g];
            out[((size_t)b * NN + i0 + row) * FF + g] = v;
        }
    }
}

extern "C" void kernel_launch(void* const* d_in, const int* in_sizes, int n_in,
                              void* d_out, int out_size, void* d_ws, size_t ws_size,
                              hipStream_t stream) {
    const float* x    = (const float*)d_in[0];
    const float* A    = (const float*)d_in[1];
    const float* W    = (const float*)d_in[2];
    const float* a_w  = (const float*)d_in[3];
    const float* a_b  = (const float*)d_in[4];
    const float* bias = (const float*)d_in[5];
    float* out = (float*)d_out;

    uint16_t* Ht = (uint16_t*)d_ws;                                   // BB*128*NN bf16 = 2 MB
    float* s = (float*)((char*)d_ws + (size_t)BB * 128 * NN * 2);     // BB*NN fp32

    k1_proj<<<BB * (NN / 16), 256, 0, stream>>>(x, W, a_w, a_b, Ht, s);
    k2_attn<<<BB * (NN / 32), 512, 0, stream>>>(A, Ht, s, bias, out);
}

// Round 2
// 155.949 us; speedup vs baseline: 1.2185x; 1.2185x over previous
//
#include <hip/hip_runtime.h>
#include <hip/hip_bf16.h>
#include <stdint.h>

#define BB 4
#define NN 2048
#define FF 128

typedef __attribute__((ext_vector_type(8))) short bf16x8;
typedef __attribute__((ext_vector_type(4))) float f32x4;

__device__ inline unsigned pk_bf16(float a, float b) {
    union { float f; unsigned u; } x, y;
    x.f = a; y.f = b;
    unsigned xu = x.u + (0x7fffu + ((x.u >> 16) & 1u));
    unsigned yu = y.u + (0x7fffu + ((y.u >> 16) & 1u));
    return (xu >> 16) | (yu & 0xffff0000u);
}

// ---------------- Kernel 1: h = x@W (fp32), s = h@a_w + a_b, Ht (bf16, transposed) ----
// grid: BB * (NN/32) = 256 blocks, 256 threads, 32 rows/block (one scheduling round)
__global__ __launch_bounds__(256) void k1_proj(
    const float* __restrict__ x, const float* __restrict__ W,
    const float* __restrict__ a_w, const float* __restrict__ a_b,
    uint16_t* __restrict__ Ht, float* __restrict__ s_out)
{
    __shared__ float Wl[128 * 128];   // 64 KB
    __shared__ float xl[32 * 128];    // 16 KB
    __shared__ float ht[128 * 33];    // h transposed [g][n], +1 pad
    __shared__ float awl[128];
    __shared__ float sred[64];

    const int t = threadIdx.x;
    const int b = blockIdx.x >> 6;
    const int n0 = (blockIdx.x & 63) << 5;

    // stage W (4096 float4), x-tile (1024 float4), a_w — all batched/coalesced
    {
        const float4* Wg = (const float4*)W;
        float4* Wd = (float4*)Wl;
        #pragma unroll
        for (int i = 0; i < 16; ++i) Wd[i * 256 + t] = Wg[i * 256 + t];
        const float4* xg = (const float4*)(x + ((size_t)(b * NN + n0)) * FF);
        float4* xd = (float4*)xl;
        #pragma unroll
        for (int i = 0; i < 4; ++i) xd[i * 256 + t] = xg[i * 256 + t];
        if (t < 32) ((float4*)awl)[t] = ((const float4*)a_w)[t];
    }
    __syncthreads();

    const int c4 = (t & 31) * 4;   // 4 output cols
    const int rb = t >> 5;         // rows rb + 8*rr, rr=0..3
    float acc[4][4] = {};

    #pragma unroll 4
    for (int k = 0; k < 128; ++k) {
        float4 wv = *(const float4*)&Wl[k * 128 + c4];
        float xv[4];
        #pragma unroll
        for (int rr = 0; rr < 4; ++rr) xv[rr] = xl[(rb + 8 * rr) * 128 + k];
        #pragma unroll
        for (int rr = 0; rr < 4; ++rr) {
            acc[rr][0] += xv[rr] * wv.x; acc[rr][1] += xv[rr] * wv.y;
            acc[rr][2] += xv[rr] * wv.z; acc[rr][3] += xv[rr] * wv.w;
        }
    }
    #pragma unroll
    for (int rr = 0; rr < 4; ++rr)
        #pragma unroll
        for (int i = 0; i < 4; ++i)
            ht[(c4 + i) * 33 + rb + 8 * rr] = acc[rr][i];
    __syncthreads();

    // s = h @ a_w + a_b : 64 threads, (row, half-of-g)
    if (t < 64) {
        const int row = t & 31, half = t >> 5;
        float sum = 0.f;
        const int g0 = half * 64;
        #pragma unroll 8
        for (int g = g0; g < g0 + 64; ++g) sum += ht[g * 33 + row] * awl[g];
        sred[half * 32 + row] = sum;
    }
    __syncthreads();
    if (t < 32) s_out[b * NN + n0 + t] = sred[t] + sred[32 + t] + a_b[0];

    // write Ht[b][g][n] bf16, packed as uint32 (2 n's) — coalesced 64B per 16 lanes
    {
        const int u = t & 15, g0 = t >> 4;
        #pragma unroll
        for (int p = 0; p < 8; ++p) {
            const int g = g0 + 16 * p;
            float v0 = ht[g * 33 + 2 * u];
            float v1 = ht[g * 33 + 2 * u + 1];
            ((unsigned*)(Ht + ((size_t)(b * 128 + g)) * NN + n0))[u] = pk_bf16(v0, v1);
        }
    }
}

// ---------------- Kernel 2: fused scores + softmax + P@H ----------------------------
// grid: BB * (NN/16) = 512 blocks, 256 threads (4 waves), 16 i-rows per block.
// Wave w handles j-chunks c == w (mod 4), chunk = 32 j's (16 per wave).
// All 8 Ht b128 loads batched into registers BEFORE the MFMAs (MLP); A/s for
// chunk c+4 register-double-buffered, issued AFTER the hb batch so the hb
// waitcnt leaves the prefetch in flight.
__global__ __launch_bounds__(256) void k2_attn(
    const float* __restrict__ A, const uint16_t* __restrict__ Ht,
    const float* __restrict__ s, const float* __restrict__ bias,
    float* __restrict__ out)
{
    __shared__ float Op[16 * 132];
    __shared__ float rsums[16];
    __shared__ float rsp[4 * 64];

    const int t = threadIdx.x;
    const int w = t >> 6, l = t & 63;
    const int b = blockIdx.x >> 7;
    const int i0 = (blockIdx.x & 127) << 4;
    const int m16 = l & 15, q = l >> 4;

    for (int i = t; i < 16 * 132; i += 256) Op[i] = 0.f;
    __syncthreads();

    const float* sb = s + b * NN;
    const float* Arow = A + ((size_t)b * NN + i0 + m16) * NN;
    const uint16_t* Hb = Ht + (size_t)b * 128 * NN;
    const float si = sb[i0 + m16];

    f32x4 acc[8] = {};
    float rs = 0.f;

    // prefetch first chunk's A/s
    const int jq = q * 8;
    float4 a0 = *(const float4*)(Arow + w * 32 + jq);
    float4 a1 = *(const float4*)(Arow + w * 32 + jq + 4);
    float4 s0 = *(const float4*)(sb + w * 32 + jq);
    float4 s1 = *(const float4*)(sb + w * 32 + jq + 4);

    for (int c = w; c < 64; c += 4) {
        const int jbc = c * 32 + jq;

        // batched Ht fragment loads (8 × b128 in flight together)
        bf16x8 hb[8];
        #pragma unroll
        for (int t8 = 0; t8 < 8; ++t8)
            hb[t8] = *(const bf16x8*)(Hb + ((size_t)(t8 * 16 + m16)) * NN + jbc);

        // prefetch next chunk (wrapped index on last iter; result unused then)
        const int jn = ((c + 4) & 63) * 32 + jq;
        float4 na0 = *(const float4*)(Arow + jn);
        float4 na1 = *(const float4*)(Arow + jn + 4);
        float4 ns0 = *(const float4*)(sb + jn);
        float4 ns1 = *(const float4*)(sb + jn + 4);

        const float sj[8] = {s0.x, s0.y, s0.z, s0.w, s1.x, s1.y, s1.z, s1.w};
        const float av[8] = {a0.x, a0.y, a0.z, a0.w, a1.x, a1.y, a1.z, a1.w};

        float p[8];
        #pragma unroll
        for (int j = 0; j < 8; ++j) {
            float e = si + sj[j];
            e = fmaxf(e, 0.2f * e);                  // LeakyReLU(0.2)
            p[j] = __expf(e + av[j]);
            rs += p[j];
        }
        union { unsigned u[4]; bf16x8 v; } fa;
        #pragma unroll
        for (int j = 0; j < 4; ++j) fa.u[j] = pk_bf16(p[2 * j], p[2 * j + 1]);

        #pragma unroll
        for (int t8 = 0; t8 < 8; ++t8)
            acc[t8] = __builtin_amdgcn_mfma_f32_16x16x32_bf16(fa.v, hb[t8], acc[t8], 0, 0, 0);

        a0 = na0; a1 = na1; s0 = ns0; s1 = ns1;
    }

    rsp[w * 64 + l] = rs;

    // accumulate O partials across waves (LDS atomics; C-layout row=q*4+r, col=m16)
    #pragma unroll
    for (int t8 = 0; t8 < 8; ++t8)
        #pragma unroll
        for (int r = 0; r < 4; ++r)
            atomicAdd(&Op[(q * 4 + r) * 132 + t8 * 16 + m16], acc[t8][r]);
    __syncthreads();

    if (t < 16) {
        float sum = 0.f;
        #pragma unroll
        for (int w2 = 0; w2 < 4; ++w2)
            #pragma unroll
            for (int q2 = 0; q2 < 4; ++q2)
                sum += rsp[w2 * 64 + q2 * 16 + t];
        rsums[t] = sum;
    }
    __syncthreads();

    // normalize + bias + write (coalesced in g)
    {
        const int g = t & 127, rh = t >> 7;
        #pragma unroll
        for (int p2 = 0; p2 < 8; ++p2) {
            const int row = rh * 8 + p2;
            out[((size_t)b * NN + i0 + row) * FF + g] = Op[row * 132 + g] / rsums[row] + bias[g];
        }
    }
}

extern "C" void kernel_launch(void* const* d_in, const int* in_sizes, int n_in,
                              void* d_out, int out_size, void* d_ws, size_t ws_size,
                              hipStream_t stream) {
    const float* x    = (const float*)d_in[0];
    const float* A    = (const float*)d_in[1];
    const float* W    = (const float*)d_in[2];
    const float* a_w  = (const float*)d_in[3];
    const float* a_b  = (const float*)d_in[4];
    const float* bias = (const float*)d_in[5];
    float* out = (float*)d_out;

    uint16_t* Ht = (uint16_t*)d_ws;                                   // BB*128*NN bf16 = 2 MB
    float* s = (float*)((char*)d_ws + (size_t)BB * 128 * NN * 2);     // BB*NN fp32

    k1_proj<<<BB * (NN / 32), 256, 0, stream>>>(x, W, a_w, a_b, Ht, s);
    k2_attn<<<BB * (NN / 16), 256, 0, stream>>>(A, Ht, s, bias, out);
}